// Round 13
// baseline (3789.439 us; speedup 1.0000x reference)
//
#include <hip/hip_runtime.h>

// Problem shape (fixed by setup_inputs): B=4, N=16384, NPOINT=1024, nsample=1,
// radius=0.5. xyz input layout is [B,3,N]. Output: int32 [B,NPOINT,1].
//
// Round-13: ALGORITHMIC cut. Rounds 0-12 established a ~3080 busy-cycle/iter
// floor for the full 16384-point scan (invariant across 5 scan/reduce
// implementations) and that cross-block sync (~1.9 us/iter, R10) is dead.
// FPS dst[] is monotone non-increasing; a new centroid only affects points
// within the shrinking covering radius r_t ~ t^(-1/3). So: Morton-sort each
// batch once (4 bits/dim, 4096 cells) so each thread owns 32 spatially
// compact points with a bounding box; per iteration a thread whose box
// satisfies lb(c,box)*0.999 >= its_max_dst provably has NO dst change
// (margin 1e-3 >> RN error of the exact scan -> conservative, never wrong);
// a wave where __all threads pass skips the whole scan AND its DPP reduce
// (persisted per-thread best key + persisted wave key stay valid).
// Exactness: scan math is the byte-exact RN chain of rounds 0-12; argmax is
// u64 keys (value<<32 | 16383-orig_idx) -> (max value, tie -> min ORIGINAL
// index) == numpy argmax, independent of point order, so the sort (and its
// nondeterministic within-cell order) cannot change results.
// Workspace: cent[B*NPOINT] + per batch {sx,sy,sz,sidx}[N] (~1.06 MB). If
// ws_size is too small: identity fallback (no sort, strided layout, boxes
// huge -> never skip) == R6 behavior.

constexpr int N_PTS  = 16384;
constexpr int NPOINT = 1024;
constexpr int BLOCK  = 512;            // 8 waves -> 2 waves/SIMD
constexpr int KPT    = N_PTS / BLOCK;  // 32 points/thread
constexpr int NWAVE  = BLOCK / 64;     // 8
constexpr int NCELL  = 4096;           // 16^3 Morton cells
constexpr int BPT    = NCELL / BLOCK;  // 8 bins/thread in prefix sum

__device__ inline unsigned long long pack_key(float v, int idx) {
    return ((unsigned long long)__float_as_uint(v) << 32) |
           (unsigned)(N_PTS - 1 - idx);
}
__device__ inline int key_idx(unsigned long long k) {
    return N_PTS - 1 - (int)(k & 0xFFFFu);
}
__device__ inline unsigned long long umax64(unsigned long long a,
                                            unsigned long long b) {
    return a > b ? a : b;
}

template <int CTRL, int RM, int BM>
__device__ inline unsigned long long dpp_max_step(unsigned long long key) {
    const int lo = (int)(unsigned)key;
    const int hi = (int)(unsigned)(key >> 32);
    const unsigned mlo =
        (unsigned)__builtin_amdgcn_update_dpp(lo, lo, CTRL, RM, BM, false);
    const unsigned mhi =
        (unsigned)__builtin_amdgcn_update_dpp(hi, hi, CTRL, RM, BM, false);
    const unsigned long long moved = ((unsigned long long)mhi << 32) | mlo;
    return key > moved ? key : moved;
}
// Full 64-lane max; result valid in ALL lanes of each row after bcasts'
// final step lands in lane 63; we only use lane 63 (HW-verified r5-r9).
__device__ inline unsigned long long wave_max_key(unsigned long long key) {
    key = dpp_max_step<0x111, 0xf, 0xf>(key);  // row_shr:1
    key = dpp_max_step<0x112, 0xf, 0xf>(key);  // row_shr:2
    key = dpp_max_step<0x114, 0xf, 0xe>(key);  // row_shr:4
    key = dpp_max_step<0x118, 0xf, 0xc>(key);  // row_shr:8
    key = dpp_max_step<0x142, 0xa, 0xf>(key);  // row_bcast:15
    key = dpp_max_step<0x143, 0xc, 0xf>(key);  // row_bcast:31
    return key;
}

__device__ inline unsigned part4(unsigned v) {   // spread 4 bits to stride 3
    return (v & 1u) | ((v & 2u) << 2) | ((v & 4u) << 4) | ((v & 8u) << 6);
}

// One block per batch: Morton counting-sort of the 16384 points into
// {sx,sy,sz,sidx}. Within-cell order is nondeterministic (atomicAdd) —
// harmless, see header.
__global__ __launch_bounds__(BLOCK) void sort_kernel(
    const float* __restrict__ xyz, float* __restrict__ sdat)
{
    const int b = blockIdx.x, tid = threadIdx.x;
    const float* X = xyz + (size_t)b * 3 * N_PTS;
    const float* Y = X + N_PTS;
    const float* Z = X + 2 * N_PTS;
    float* sx = sdat + (size_t)b * 4 * N_PTS;
    float* sy = sx + N_PTS;
    float* sz = sy + N_PTS;
    int*   sidx = (int*)(sz + N_PTS);

    __shared__ int hist[NCELL];
    __shared__ int part[BLOCK];
    for (int i = tid; i < NCELL; i += BLOCK) hist[i] = 0;
    __syncthreads();

    int code[KPT];
#pragma unroll
    for (int k = 0; k < KPT; ++k) {
        const int p = tid + k * BLOCK;
        const int cx = min(15, max(0, (int)(X[p] * 16.0f)));
        const int cy = min(15, max(0, (int)(Y[p] * 16.0f)));
        const int cz = min(15, max(0, (int)(Z[p] * 16.0f)));
        code[k] = (int)(part4(cx) | (part4(cy) << 1) | (part4(cz) << 2));
        atomicAdd(&hist[code[k]], 1);
    }
    __syncthreads();

    // exclusive prefix sum over the 4096 bins (8 bins/thread + block scan)
    int loc[BPT], s = 0;
#pragma unroll
    for (int j = 0; j < BPT; ++j) { loc[j] = hist[tid * BPT + j]; s += loc[j]; }
    part[tid] = s;
    __syncthreads();
    for (int off = 1; off < BLOCK; off <<= 1) {
        const int v = (tid >= off) ? part[tid - off] : 0;
        __syncthreads();
        part[tid] += v;
        __syncthreads();
    }
    int run = part[tid] - s;                   // exclusive base of my 8 bins
#pragma unroll
    for (int j = 0; j < BPT; ++j) { const int c = loc[j]; hist[tid * BPT + j] = run; run += c; }
    __syncthreads();

#pragma unroll
    for (int k = 0; k < KPT; ++k) {
        const int p = tid + k * BLOCK;
        const int pos = atomicAdd(&hist[code[k]], 1);
        sx[pos] = X[p];
        sy[pos] = Y[p];
        sz[pos] = Z[p];
        sidx[pos] = p;
    }
}

__global__ __launch_bounds__(BLOCK)
__attribute__((amdgpu_waves_per_eu(2, 2))) void fps_kernel(
    const float* __restrict__ xyz,   // [B,3,N] original
    const float* __restrict__ sdat,  // sorted {sx,sy,sz,sidx} per batch
    int* __restrict__ cent,          // [B,NPOINT]
    int use_sorted)
{
    const int b   = blockIdx.x;
    const int tid = threadIdx.x;
    const float* X = xyz + (size_t)b * 3 * N_PTS;
    const float* Y = X + N_PTS;
    const float* Z = X + 2 * N_PTS;
    const float* sx = sdat + (size_t)b * 4 * N_PTS;
    const float* sy = sx + N_PTS;
    const float* sz = sy + N_PTS;
    const int* sidx = (const int*)(sz + N_PTS);
    const int base = tid * KPT;

    float px[KPT], py[KPT], pz[KPT], dst[KPT];
    float bnx =  1e30f, bny =  1e30f, bnz =  1e30f;   // box min
    float bxx = -1e30f, bxy = -1e30f, bxz = -1e30f;   // box max
#pragma unroll
    for (int k = 0; k < KPT; ++k) {
        float x, y, z;
        if (use_sorted) { x = sx[base + k]; y = sy[base + k]; z = sz[base + k]; }
        else { const int p = tid + k * BLOCK; x = X[p]; y = Y[p]; z = Z[p]; }
        px[k] = x; py[k] = y; pz[k] = z;
        bnx = fminf(bnx, x); bny = fminf(bny, y); bnz = fminf(bnz, z);
        bxx = fmaxf(bxx, x); bxy = fmaxf(bxy, y); bxz = fmaxf(bxz, z);
        dst[k] = 1e10f;                  // BIG
    }

    __shared__ unsigned long long s_key[2][NWAVE];  // double-buffered

    const int wave = tid >> 6;
    const int lane = tid & 63;

    // ---- initial far: argmax over x by (value, tie -> min orig idx) keys
    int far;
    {
        unsigned long long tk = 0ull;
#pragma unroll
        for (int k = 0; k < KPT; ++k) {
            const int id = use_sorted ? sidx[base + k] : tid + k * BLOCK;
            tk = umax64(tk, pack_key(px[k], id));
        }
        const unsigned long long key = wave_max_key(tk);
        if (lane == 63) s_key[0][wave] = key;
        __syncthreads();
        const unsigned long long* sk = s_key[0];
        const unsigned long long bkk =
            umax64(umax64(umax64(sk[0], sk[1]), umax64(sk[2], sk[3])),
                   umax64(umax64(sk[4], sk[5]), umax64(sk[6], sk[7])));
        far = __builtin_amdgcn_readfirstlane(key_idx(bkk)) & (N_PTS - 1);
    }

    float bv = 1e10f;                     // thread max dst (skip test)
    unsigned long long tkey = 0ull;       // persisted thread best key
    unsigned long long wkey = 0ull;       // persisted wave-reduced key

    // ---- main FPS loop: one barrier per iteration ----
    for (int it = 0; it < NPOINT; ++it) {
        if (tid == 0) cent[b * NPOINT + it] = far;   // record PRE-update far
        if (it == NPOINT - 1) break;                 // last update is unused

        // centroid coords (original arrays; far uniform -> scalar loads)
        const float cx = X[far];
        const float cy = Y[far];
        const float cz = Z[far];

        // conservative box lower-bound test (margin 1e-3 >> RN error):
        // if lb*0.999 >= bv then no point of this thread can change.
        const float tx = fmaxf(fmaxf(bnx - cx, cx - bxx), 0.0f);
        const float ty = fmaxf(fmaxf(bny - cy, cy - bxy), 0.0f);
        const float tz = fmaxf(fmaxf(bnz - cz, cz - bxz), 0.0f);
        const float lb = tx * tx + ty * ty + tz * tz;
        const bool nosck = (lb * 0.999f >= bv);

        if (!__all((int)nosck)) {        // wave-uniform: someone must rescan
            unsigned long long tk = 0ull;
#pragma unroll
            for (int k = 0; k < KPT; ++k) {
                const float dx = __fsub_rn(px[k], cx);
                const float dy = __fsub_rn(py[k], cy);
                const float dz = __fsub_rn(pz[k], cz);
                const float d  = __fadd_rn(
                    __fadd_rn(__fmul_rn(dx, dx), __fmul_rn(dy, dy)),
                    __fmul_rn(dz, dz));
                const float nd = fminf(dst[k], d);
                dst[k] = nd;
                const int id = use_sorted ? sidx[base + k] : tid + k * BLOCK;
                tk = umax64(tk, pack_key(nd, id));
            }
            tkey = tk;
            bv = __uint_as_float((unsigned)(tkey >> 32));
            wkey = wave_max_key(tkey);
        }
        const int buf = (it + 1) & 1;
        if (lane == 63) s_key[buf][wave] = wkey;
        __syncthreads();

        const unsigned long long* sk = s_key[buf];
        const unsigned long long bkk =
            umax64(umax64(umax64(sk[0], sk[1]), umax64(sk[2], sk[3])),
                   umax64(umax64(sk[4], sk[5]), umax64(sk[6], sk[7])));
        far = __builtin_amdgcn_readfirstlane(key_idx(bkk)) & (N_PTS - 1);
    }
}

// ---------------------------------------------------------------------------
// Ball query, nsample=1 (unchanged, original indices throughout).
// ---------------------------------------------------------------------------
__global__ __launch_bounds__(256) void ballq_kernel(
    const float* __restrict__ xyz,   // [B,3,N]
    const int* __restrict__ cent,    // [B,NPOINT]
    int* __restrict__ out)           // [B,NPOINT]
{
    const int gw   = (blockIdx.x * 256 + threadIdx.x) >> 6; // global wave id
    const int lane = threadIdx.x & 63;
    const int b = gw / NPOINT;
    const int s = gw % NPOINT;

    const float* X = xyz + (size_t)b * 3 * N_PTS;
    const float* Y = X + N_PTS;
    const float* Z = X + 2 * N_PTS;

    const int ci = cent[b * NPOINT + s] & (N_PTS - 1);  // fault guard
    const float cx = X[ci];
    const float cy = Y[ci];
    const float cz = Z[ci];
    const float cn = __fadd_rn(
        __fadd_rn(__fmul_rn(cx, cx), __fmul_rn(cy, cy)), __fmul_rn(cz, cz));

    int res = N_PTS;
    for (int base = 0; base < N_PTS; base += 64) {
        const int p = base + lane;
        const float x = X[p];
        const float y = Y[p];
        const float z = Z[p];
        const float dot = __fadd_rn(
            __fadd_rn(__fmul_rn(x, cx), __fmul_rn(y, cy)), __fmul_rn(z, cz));
        const float pn = __fadd_rn(
            __fadd_rn(__fmul_rn(x, x), __fmul_rn(y, y)), __fmul_rn(z, z));
        const float d = __fadd_rn(__fadd_rn(__fmul_rn(-2.0f, dot), cn), pn);
        const bool hit = !(d > 0.25f);
        const unsigned long long m = __ballot(hit);
        if (m) {                       // wave-uniform branch
            res = base + (__ffsll((long long)m) - 1);
            break;
        }
    }
    if (lane == 0) out[b * NPOINT + s] = res;
}

extern "C" void kernel_launch(void* const* d_in, const int* in_sizes, int n_in,
                              void* d_out, int out_size, void* d_ws, size_t ws_size,
                              hipStream_t stream) {
    const float* xyz = (const float*)d_in[0];
    const int B = in_sizes[1] / 16;          // cls_label is [B,16]
    int* cent = (int*)d_ws;                  // [B, NPOINT]
    const size_t cent_bytes = (size_t)B * NPOINT * 4;
    float* sdat = (float*)((char*)d_ws + cent_bytes);
    const size_t need = cent_bytes + (size_t)B * 4 * N_PTS * 4;
    const int use_sorted = (ws_size >= need) ? 1 : 0;
    int* out = (int*)d_out;                  // int32 [B, NPOINT, 1]

    if (use_sorted)
        sort_kernel<<<B, BLOCK, 0, stream>>>(xyz, sdat);
    fps_kernel<<<B, BLOCK, 0, stream>>>(xyz, sdat, cent, use_sorted);

    const int nwaves  = B * NPOINT;          // one wave per centroid
    const int nblocks = nwaves / 4;          // 256 threads = 4 waves/block
    ballq_kernel<<<nblocks, 256, 0, stream>>>(xyz, cent, out);
}

// Round 14
// 1877.000 us; speedup vs baseline: 2.0189x; 2.0189x over previous
//
#include <hip/hip_runtime.h>

// Problem shape (fixed by setup_inputs): B=4, N=16384, NPOINT=1024, nsample=1,
// radius=0.5. xyz input layout is [B,3,N]. Output: int32 [B,NPOINT,1].
//
// Round-14: R13's algorithmic skip (HW-verified exact: Morton sort + per-
// thread bounding-box lower-bound test; VALU work halved) with its two
// latency leaks fixed:
//  1. orig-index lookups (sidx) move to LDS, read as int4 with compile-time
//     indices -> ZERO global loads inside the scan (R13 re-issued 32 global
//     loads per rescan).
//  2. fps warms the original xyz arrays into its own XCD's L2 at init
//     (strided dummy read kept alive by an asm sink) -> the per-iteration
//     X/Y/Z[far] scalar loads are ~200-cyc L2 hits again (R13 left xyz cold:
//     3 serialized ~900-cyc HBM misses per iteration).
// Exactness unchanged from R13 (passed, absmax 0): scan math is the byte-
// exact RN chain; argmax via u64 keys (value<<32 | 16383-orig_idx) == numpy
// (max value, tie -> min ORIGINAL index), independent of sort order; skip
// test lb*0.999 >= thread_max_dst is conservative (1e-3 margin >> RN error).
// Workspace: cent[B*NPOINT] + per batch {sx,sy,sz,sidx}[N]. If ws too small:
// identity fallback == R6 behavior (no sort, never-skip boxes).

constexpr int N_PTS  = 16384;
constexpr int NPOINT = 1024;
constexpr int BLOCK  = 512;            // 8 waves -> 2 waves/SIMD
constexpr int KPT    = N_PTS / BLOCK;  // 32 points/thread
constexpr int NWAVE  = BLOCK / 64;     // 8
constexpr int NCELL  = 4096;           // 16^3 Morton cells
constexpr int BPT    = NCELL / BLOCK;  // 8 bins/thread in prefix sum

__device__ inline unsigned long long pack_key(float v, int idx) {
    return ((unsigned long long)__float_as_uint(v) << 32) |
           (unsigned)(N_PTS - 1 - idx);
}
__device__ inline int key_idx(unsigned long long k) {
    return N_PTS - 1 - (int)(k & 0xFFFFu);
}
__device__ inline unsigned long long umax64(unsigned long long a,
                                            unsigned long long b) {
    return a > b ? a : b;
}

template <int CTRL, int RM, int BM>
__device__ inline unsigned long long dpp_max_step(unsigned long long key) {
    const int lo = (int)(unsigned)key;
    const int hi = (int)(unsigned)(key >> 32);
    const unsigned mlo =
        (unsigned)__builtin_amdgcn_update_dpp(lo, lo, CTRL, RM, BM, false);
    const unsigned mhi =
        (unsigned)__builtin_amdgcn_update_dpp(hi, hi, CTRL, RM, BM, false);
    const unsigned long long moved = ((unsigned long long)mhi << 32) | mlo;
    return key > moved ? key : moved;
}
// Full 64-lane max; result valid in lane 63 (HW-verified rounds 5-13).
__device__ inline unsigned long long wave_max_key(unsigned long long key) {
    key = dpp_max_step<0x111, 0xf, 0xf>(key);  // row_shr:1
    key = dpp_max_step<0x112, 0xf, 0xf>(key);  // row_shr:2
    key = dpp_max_step<0x114, 0xf, 0xe>(key);  // row_shr:4
    key = dpp_max_step<0x118, 0xf, 0xc>(key);  // row_shr:8
    key = dpp_max_step<0x142, 0xa, 0xf>(key);  // row_bcast:15
    key = dpp_max_step<0x143, 0xc, 0xf>(key);  // row_bcast:31
    return key;
}

__device__ inline unsigned part4(unsigned v) {   // spread 4 bits to stride 3
    return (v & 1u) | ((v & 2u) << 2) | ((v & 4u) << 4) | ((v & 8u) << 6);
}

// One block per batch: Morton counting-sort into {sx,sy,sz,sidx}
// (HW-verified R13; within-cell order nondeterminism harmless — see header).
__global__ __launch_bounds__(BLOCK) void sort_kernel(
    const float* __restrict__ xyz, float* __restrict__ sdat)
{
    const int b = blockIdx.x, tid = threadIdx.x;
    const float* X = xyz + (size_t)b * 3 * N_PTS;
    const float* Y = X + N_PTS;
    const float* Z = X + 2 * N_PTS;
    float* sx = sdat + (size_t)b * 4 * N_PTS;
    float* sy = sx + N_PTS;
    float* sz = sy + N_PTS;
    int*   sidx = (int*)(sz + N_PTS);

    __shared__ int hist[NCELL];
    __shared__ int part[BLOCK];
    for (int i = tid; i < NCELL; i += BLOCK) hist[i] = 0;
    __syncthreads();

    int code[KPT];
#pragma unroll
    for (int k = 0; k < KPT; ++k) {
        const int p = tid + k * BLOCK;
        const int cx = min(15, max(0, (int)(X[p] * 16.0f)));
        const int cy = min(15, max(0, (int)(Y[p] * 16.0f)));
        const int cz = min(15, max(0, (int)(Z[p] * 16.0f)));
        code[k] = (int)(part4(cx) | (part4(cy) << 1) | (part4(cz) << 2));
        atomicAdd(&hist[code[k]], 1);
    }
    __syncthreads();

    int loc[BPT], s = 0;
#pragma unroll
    for (int j = 0; j < BPT; ++j) { loc[j] = hist[tid * BPT + j]; s += loc[j]; }
    part[tid] = s;
    __syncthreads();
    for (int off = 1; off < BLOCK; off <<= 1) {
        const int v = (tid >= off) ? part[tid - off] : 0;
        __syncthreads();
        part[tid] += v;
        __syncthreads();
    }
    int run = part[tid] - s;
#pragma unroll
    for (int j = 0; j < BPT; ++j) { const int c = loc[j]; hist[tid * BPT + j] = run; run += c; }
    __syncthreads();

#pragma unroll
    for (int k = 0; k < KPT; ++k) {
        const int p = tid + k * BLOCK;
        const int pos = atomicAdd(&hist[code[k]], 1);
        sx[pos] = X[p];
        sy[pos] = Y[p];
        sz[pos] = Z[p];
        sidx[pos] = p;
    }
}

__global__ __launch_bounds__(BLOCK)
__attribute__((amdgpu_waves_per_eu(2, 2))) void fps_kernel(
    const float* __restrict__ xyz,   // [B,3,N] original
    const float* __restrict__ sdat,  // sorted {sx,sy,sz,sidx} per batch
    int* __restrict__ cent,          // [B,NPOINT]
    int use_sorted)
{
    const int b   = blockIdx.x;
    const int tid = threadIdx.x;
    const float* X = xyz + (size_t)b * 3 * N_PTS;
    const float* Y = X + N_PTS;
    const float* Z = X + 2 * N_PTS;
    const float* sx = sdat + (size_t)b * 4 * N_PTS;
    const float* sy = sx + N_PTS;
    const float* sz = sy + N_PTS;
    const int* sidx = (const int*)(sz + N_PTS);
    const int base = tid * KPT;

    // orig indices live in LDS: zero global loads inside the scan loop.
    __shared__ int s_sid[N_PTS];                    // 64 KB
    __shared__ unsigned long long s_key[2][NWAVE];  // double-buffered

    float px[KPT], py[KPT], pz[KPT], dst[KPT];
    float bnx =  1e30f, bny =  1e30f, bnz =  1e30f;   // box min
    float bxx = -1e30f, bxy = -1e30f, bxz = -1e30f;   // box max
#pragma unroll
    for (int k = 0; k < KPT; ++k) {
        float x, y, z;
        int id;
        if (use_sorted) {
            x = sx[base + k]; y = sy[base + k]; z = sz[base + k];
            id = sidx[base + k];
        } else {
            const int p = tid + k * BLOCK;
            x = X[p]; y = Y[p]; z = Z[p];
            id = p;
        }
        s_sid[base + k] = id;
        px[k] = x; py[k] = y; pz[k] = z;
        bnx = fminf(bnx, x); bny = fminf(bny, y); bnz = fminf(bnz, z);
        bxx = fmaxf(bxx, x); bxy = fmaxf(bxy, y); bxz = fmaxf(bxz, z);
        dst[k] = 1e10f;                  // BIG
    }

    // Warm original xyz into THIS block's XCD L2 so the per-iteration
    // X/Y/Z[far] scalar loads are L2 hits (R13's cold misses were ~900 cyc
    // serialized per iteration). asm sink keeps the reads alive.
    if (use_sorted) {
        float w = 0.0f;
        for (int i = tid; i < 3 * N_PTS; i += BLOCK) w += X[i];
        asm volatile("" :: "v"(w));
    }

    const int wave = tid >> 6;
    const int lane = tid & 63;

    // ---- initial far: argmax over x by (value, tie -> min orig idx) keys
    // (the barrier also publishes s_sid for the main loop)
    int far;
    {
        unsigned long long tk = 0ull;
#pragma unroll
        for (int k = 0; k < KPT; ++k)
            tk = umax64(tk, pack_key(px[k], s_sid[base + k]));
        const unsigned long long key = wave_max_key(tk);
        if (lane == 63) s_key[0][wave] = key;
        __syncthreads();
        const unsigned long long* sk = s_key[0];
        const unsigned long long bkk =
            umax64(umax64(umax64(sk[0], sk[1]), umax64(sk[2], sk[3])),
                   umax64(umax64(sk[4], sk[5]), umax64(sk[6], sk[7])));
        far = __builtin_amdgcn_readfirstlane(key_idx(bkk)) & (N_PTS - 1);
    }

    float bv = 1e10f;                     // thread max dst (skip test)
    unsigned long long wkey = 0ull;       // persisted wave-reduced key
    const int4* sidv = (const int4*)&s_sid[base];   // 128B-aligned

    // ---- main FPS loop: one barrier per iteration ----
    for (int it = 0; it < NPOINT; ++it) {
        if (tid == 0) cent[b * NPOINT + it] = far;   // record PRE-update far
        if (it == NPOINT - 1) break;                 // last update is unused

        // centroid coords (warm L2; far uniform -> scalar broadcast loads)
        const float cx = X[far];
        const float cy = Y[far];
        const float cz = Z[far];

        // conservative box lower-bound test (margin 1e-3 >> RN error)
        const float tx = fmaxf(fmaxf(bnx - cx, cx - bxx), 0.0f);
        const float ty = fmaxf(fmaxf(bny - cy, cy - bxy), 0.0f);
        const float tz = fmaxf(fmaxf(bnz - cz, cz - bxz), 0.0f);
        const float lb = tx * tx + ty * ty + tz * tz;
        const bool nosck = (lb * 0.999f >= bv);

        if (!__all((int)nosck)) {        // wave-uniform: someone must rescan
            unsigned long long tk = 0ull;
#pragma unroll
            for (int j = 0; j < KPT / 4; ++j) {
                const int4 sv = sidv[j];   // 4 orig ids, one ds_read_b128
#pragma unroll
                for (int q = 0; q < 4; ++q) {
                    const int k = 4 * j + q;
                    const float dx = __fsub_rn(px[k], cx);
                    const float dy = __fsub_rn(py[k], cy);
                    const float dz = __fsub_rn(pz[k], cz);
                    const float d  = __fadd_rn(
                        __fadd_rn(__fmul_rn(dx, dx), __fmul_rn(dy, dy)),
                        __fmul_rn(dz, dz));
                    const float nd = fminf(dst[k], d);
                    dst[k] = nd;
                    const int id = (q == 0) ? sv.x : (q == 1) ? sv.y
                                 : (q == 2) ? sv.z : sv.w;
                    tk = umax64(tk, pack_key(nd, id));
                }
            }
            bv = __uint_as_float((unsigned)(tk >> 32));
            wkey = wave_max_key(tk);
        }
        const int buf = (it + 1) & 1;
        if (lane == 63) s_key[buf][wave] = wkey;
        __syncthreads();

        const unsigned long long* sk = s_key[buf];
        const unsigned long long bkk =
            umax64(umax64(umax64(sk[0], sk[1]), umax64(sk[2], sk[3])),
                   umax64(umax64(sk[4], sk[5]), umax64(sk[6], sk[7])));
        far = __builtin_amdgcn_readfirstlane(key_idx(bkk)) & (N_PTS - 1);
    }
}

// ---------------------------------------------------------------------------
// Ball query, nsample=1 (unchanged, original indices throughout).
// ---------------------------------------------------------------------------
__global__ __launch_bounds__(256) void ballq_kernel(
    const float* __restrict__ xyz,   // [B,3,N]
    const int* __restrict__ cent,    // [B,NPOINT]
    int* __restrict__ out)           // [B,NPOINT]
{
    const int gw   = (blockIdx.x * 256 + threadIdx.x) >> 6; // global wave id
    const int lane = threadIdx.x & 63;
    const int b = gw / NPOINT;
    const int s = gw % NPOINT;

    const float* X = xyz + (size_t)b * 3 * N_PTS;
    const float* Y = X + N_PTS;
    const float* Z = X + 2 * N_PTS;

    const int ci = cent[b * NPOINT + s] & (N_PTS - 1);  // fault guard
    const float cx = X[ci];
    const float cy = Y[ci];
    const float cz = Z[ci];
    const float cn = __fadd_rn(
        __fadd_rn(__fmul_rn(cx, cx), __fmul_rn(cy, cy)), __fmul_rn(cz, cz));

    int res = N_PTS;
    for (int base = 0; base < N_PTS; base += 64) {
        const int p = base + lane;
        const float x = X[p];
        const float y = Y[p];
        const float z = Z[p];
        const float dot = __fadd_rn(
            __fadd_rn(__fmul_rn(x, cx), __fmul_rn(y, cy)), __fmul_rn(z, cz));
        const float pn = __fadd_rn(
            __fadd_rn(__fmul_rn(x, x), __fmul_rn(y, y)), __fmul_rn(z, z));
        const float d = __fadd_rn(__fadd_rn(__fmul_rn(-2.0f, dot), cn), pn);
        const bool hit = !(d > 0.25f);
        const unsigned long long m = __ballot(hit);
        if (m) {                       // wave-uniform branch
            res = base + (__ffsll((long long)m) - 1);
            break;
        }
    }
    if (lane == 0) out[b * NPOINT + s] = res;
}

extern "C" void kernel_launch(void* const* d_in, const int* in_sizes, int n_in,
                              void* d_out, int out_size, void* d_ws, size_t ws_size,
                              hipStream_t stream) {
    const float* xyz = (const float*)d_in[0];
    const int B = in_sizes[1] / 16;          // cls_label is [B,16]
    int* cent = (int*)d_ws;                  // [B, NPOINT]
    const size_t cent_bytes = (size_t)B * NPOINT * 4;
    float* sdat = (float*)((char*)d_ws + cent_bytes);
    const size_t need = cent_bytes + (size_t)B * 4 * N_PTS * 4;
    const int use_sorted = (ws_size >= need) ? 1 : 0;
    int* out = (int*)d_out;                  // int32 [B, NPOINT, 1]

    if (use_sorted)
        sort_kernel<<<B, BLOCK, 0, stream>>>(xyz, sdat);
    fps_kernel<<<B, BLOCK, 0, stream>>>(xyz, sdat, cent, use_sorted);

    const int nwaves  = B * NPOINT;          // one wave per centroid
    const int nblocks = nwaves / 4;          // 256 threads = 4 waves/block
    ballq_kernel<<<nblocks, 256, 0, stream>>>(xyz, cent, out);
}